// Round 8
// baseline (182.201 us; speedup 1.0000x reference)
//
#include <hip/hip_runtime.h>
#include <math.h>

// ---------------------------------------------------------------------------
// Grok5PhiCore: out = proj( softmax(QK^T*scale + phi_bias) V ).
// B=2, L=2048, D=1024, H=16, Dh=64.
//
// v14 (attn: 2 j-tiles per barrier period):
//  - attn stages TWO 64-j K/V tiles (32KB) per barrier period and computes
//    both between barriers: barrier events per block HALVE (64 -> 32).
//    v13's 23% all-pipes-idle fraction is barrier/drain convoy; amortizing
//    the drain over 2x compute reclaims ~half of it. Per-wave inner code
//    is byte-identical (applied per sub-tile); LDS 33.3KB keeps 4 blocks/CU.
//  - everything else unchanged from v13 (XCD-pinned heads, fused prep,
//    fused V tile-major epilogue in QKV GEMM).
//
// Workspace (48 MB, fp16):
//   xb    [4096][1024]   8 MB   x cast
//   wqkvT [3072][1024]   6 MB   w_qkv transposed
//   wpT   [1024][1024]   2 MB   w_proj transposed
//   qb    [32][2048][64] 8 MB   Q per head, PRE-SCALED by 0.125*log2e
//   kb    [32][2048][64] 8 MB   K per head
//   vb    [32][32][64][64] 8 MB V per head, tile-major, j-permuted
//   ctx   [4096][1024]   8 MB   attn output
// ---------------------------------------------------------------------------

typedef _Float16 f16;
typedef _Float16 f16x4 __attribute__((ext_vector_type(4)));
typedef _Float16 f16x8 __attribute__((ext_vector_type(8)));
typedef float f32x4 __attribute__((ext_vector_type(4)));

#define MFMA32(a, b, c) __builtin_amdgcn_mfma_f32_16x16x32_f16(a, b, c, 0, 0, 0)

static constexpr int Bsz = 2, Lseq = 2048, Dm = 1024, H = 16, Dh = 64;
static constexpr int Mtot = Bsz * Lseq;        // 4096
static constexpr int NQKV = 3 * Dm;            // 3072
static constexpr float PHI_F = 1.61803398874989484820f;
static constexpr float LOG2E = 1.44269504088896f;
static constexpr float QS = 0.125f * LOG2E;    // folded into stored q
static constexpr float CSTEP = 0.55417527999932633f;  // fract(64*phi)

// async 16B global -> LDS (lds dest = wave-uniform base + lane*16)
__device__ __forceinline__ void load16_to_lds(const f16* g, f16* l) {
  __builtin_amdgcn_global_load_lds(
      (const __attribute__((address_space(1))) unsigned int*)g,
      (__attribute__((address_space(3))) unsigned int*)l, 16, 0, 0);
}

// ---------------- fused prep: cast + 2 transposes --------------------------
// grid sections: [0,4096) cast x; [4096,7168) transpose w_qkv;
// [7168,8192) transpose w_proj. 256 threads.
__global__ __launch_bounds__(256) void prep_fused(
    const float* __restrict__ x, f16* __restrict__ xb,
    const float* __restrict__ wqkv, f16* __restrict__ wqkvT,
    const float* __restrict__ wproj, f16* __restrict__ wpT) {
  __shared__ float tile[32][33];
  int blk = blockIdx.x;
  if (blk < 4096) {
    int i = (blk * 256 + threadIdx.x) * 4;
    float4 v = *reinterpret_cast<const float4*>(x + i);
    f16 t[4] = {(f16)v.x, (f16)v.y, (f16)v.z, (f16)v.w};
    *reinterpret_cast<uint2*>(xb + i) = *reinterpret_cast<uint2*>(t);
    return;
  }
  const float* in;
  f16* out;
  int N, bx, by;
  if (blk < 7168) {
    int local = blk - 4096;
    bx = local % 96; by = local / 96; N = NQKV;
    in = wqkv; out = wqkvT;
  } else {
    int local = blk - 7168;
    bx = local & 31; by = local >> 5; N = Dm;
    in = wproj; out = wpT;
  }
  int n0 = bx * 32, k0 = by * 32;  // K = Dm always
  int tx = threadIdx.x & 31, ty = threadIdx.x >> 5;  // 32 x 8
#pragma unroll
  for (int r = 0; r < 32; r += 8)
    tile[ty + r][tx] = in[(size_t)(k0 + ty + r) * N + n0 + tx];
  __syncthreads();
#pragma unroll
  for (int r = 0; r < 32; r += 8)
    out[(size_t)(n0 + ty + r) * Dm + k0 + tx] = (f16)tile[tx][ty + r];
}

// ---------------- GEMM: C[M,N] = A[M,K] * Bt[N,K]^T  (fp16, fp32 acc) ------
// m97-style: global_load_lds(16B) staging, BK=64, unpadded LDS with
// global-side XOR chunk swizzle. MODE 0: 128x128 tile, QKV scatter epilogue
// (V written tile-major j-permuted, packed uint2). MODE 1: 64x128, fp32+bias.
template <int MODE>
__global__ __launch_bounds__(256) void gemm_f16(
    const f16* __restrict__ A, const f16* __restrict__ Bt,
    int M, int N, int K,
    f16* __restrict__ qb, f16* __restrict__ kb, f16* __restrict__ vb,
    float* __restrict__ out, const float* __restrict__ bias) {
  constexpr int BM = (MODE == 0) ? 128 : 64;
  constexpr int MI = BM / 32;          // m-frags per wave (4 or 2)
  constexpr int AI = BM / 32;          // A staging iters per thread (4 or 2)
  __shared__ f16 As[BM * 64];
  __shared__ f16 Bs[128 * 64];

  int tid = threadIdx.x;
  int wave = tid >> 6, lane = tid & 63;
  int quad = lane >> 4, l16 = lane & 15;
  int wm = (wave >> 1) * (MI * 16), wn = (wave & 1) * 64;

  // XCD-locality swizzle (1-D grid)
  int lid = blockIdx.x;
  int xcd = lid & 7, t = lid >> 3;
  int m0, n0;
  if (MODE == 0) {  // 32m x 24n blocks; XCD region = 8m x 12n
    int mg = xcd >> 1, ng = xcd & 1;
    m0 = (mg * 8 + t / 12) * 128;
    n0 = (ng * 12 + t % 12) * 128;
  } else {          // 64m x 8n blocks; XCD region = 8m x 8n
    m0 = (xcd * 8 + (t >> 3)) * 64;
    n0 = (t & 7) * 128;
  }

  // staging: lds chunk (64*it + lane) holds global chunk gu of row
  // (8*it + lane>>3), gu = (lane&7) ^ (lane>>3)
  const int gu = (lane & 7) ^ (lane >> 3);
  const f16* gA[AI];
  f16* lA[AI];
#pragma unroll
  for (int i = 0; i < AI; i++) {
    int it = wave * AI + i;
    gA[i] = A + (size_t)(m0 + it * 8 + (lane >> 3)) * K + gu * 8;
    lA[i] = As + it * 512;
  }
  const f16* gB[4];
  f16* lB[4];
#pragma unroll
  for (int i = 0; i < 4; i++) {
    int it = wave * 4 + i;
    gB[i] = Bt + (size_t)(n0 + it * 8 + (lane >> 3)) * K + gu * 8;
    lB[i] = Bs + it * 512;
  }

  f32x4 acc[MI][4] = {};

  for (int k0 = 0; k0 < K; k0 += 64) {
#pragma unroll
    for (int i = 0; i < AI; i++) load16_to_lds(gA[i] + k0, lA[i]);
#pragma unroll
    for (int i = 0; i < 4; i++) load16_to_lds(gB[i] + k0, lB[i]);
    __syncthreads();  // drains vmcnt before barrier
#pragma unroll
    for (int s = 0; s < 2; s++) {
      f16x8 a[MI], b[4];
#pragma unroll
      for (int i = 0; i < MI; i++) {
        int row = wm + i * 16 + l16;
        a[i] = *reinterpret_cast<const f16x8*>(
            As + row * 64 + (((s * 4 + quad) ^ (l16 & 7)) * 8));
      }
#pragma unroll
      for (int j = 0; j < 4; j++) {
        int row = wn + j * 16 + l16;
        b[j] = *reinterpret_cast<const f16x8*>(
            Bs + row * 64 + (((s * 4 + quad) ^ (l16 & 7)) * 8));
      }
#pragma unroll
      for (int i = 0; i < MI; i++)
#pragma unroll
        for (int j = 0; j < 4; j++)
          acc[i][j] = MFMA32(a[i], b[j], acc[i][j]);
    }
    __syncthreads();
  }

  // epilogue: C/D layout col = lane&15, row = quad*4 + reg
#pragma unroll
  for (int i = 0; i < MI; i++) {
#pragma unroll
    for (int j = 0; j < 4; j++) {
      int n = n0 + wn + j * 16 + l16;
      if (MODE == 0) {
        int ty = n >> 10;  // 0=q 1=k 2=v
        int df = n & 1023;
        int h = df >> 6, dh = df & 63;
        int mb = m0 + wm + i * 16 + quad * 4;  // 4-aligned; +r below
        int b = mb >> 11, l = mb & 2047;
        int bhh = b * H + h;
        if (ty == 2) {
          // V tile-major j-permuted: 4 r-values -> one contiguous 8B run.
          int jj = l & 63;
          int jh = jj >> 5, rem = jj & 31;
          int qd = (rem & 15) >> 2;
          int e0 = (rem >= 16) ? 4 : 0;
          f16x4 tmp;
#pragma unroll
          for (int r = 0; r < 4; r++) tmp[r] = (f16)acc[i][j][r];
          *reinterpret_cast<uint2*>(
              vb + (size_t)bhh * (Dh * Lseq) + (l >> 6) * 4096 + dh * 64 +
              (jh * 4 + qd) * 8 + e0) = *reinterpret_cast<uint2*>(&tmp);
        } else {
          size_t idx = (((size_t)bhh) * Lseq + l) * Dh + dh;
          if (ty == 0) {
#pragma unroll
            for (int r = 0; r < 4; r++)
              qb[idx + (size_t)r * Dh] = (f16)(acc[i][j][r] * QS);
          } else {
#pragma unroll
            for (int r = 0; r < 4; r++)
              kb[idx + (size_t)r * Dh] = (f16)acc[i][j][r];
          }
        }
      } else {
#pragma unroll
        for (int r = 0; r < 4; r++) {
          int m = m0 + wm + i * 16 + quad * 4 + r;
          out[(size_t)m * N + n] = acc[i][j][r] + bias[n];
        }
      }
    }
  }
}

// ---------------- flash attention v14 (128-q blocks, 2 j-tiles/period) -----
// grid: 512 blocks x 512 thr. Decode: xcd = id&7, t = id>>3,
// bh = xcd*4 + (t>>4) (4 heads/XCD -> 2MB K/V in per-XCD L2),
// q0 = (t&15)*128. Wave w: qq = w&3 (q-group of 32), jhalf = w>>2.
// Each barrier period stages TWO 64-j K/V tiles (32KB) and computes both:
// 32 barrier events per block (v13 had 64).
__global__ __launch_bounds__(512, 4) void attn_kernel(
    const f16* __restrict__ qb,   // [BH][L][64], pre-scaled by QS
    const f16* __restrict__ kb,   // [BH][L][64]
    const f16* __restrict__ vb,   // [BH][32 jt][64 d][64 j-perm]
    f16* __restrict__ ctx) {      // [B*L][1024]
  __shared__ __align__(16) unsigned char smem[33280];
  f16* Ks = (f16*)smem;            // [2][64][64] XOR-swizzled chunks
  f16* Vs = (f16*)(smem + 16384);  // [2][64][64] permuted + XOR-swizzled

  int id = blockIdx.x;
  int bh = (id & 7) * 4 + ((id >> 3) >> 4);
  int q0 = ((id >> 3) & 15) * 128;

  int tid = threadIdx.x, wave = tid >> 6, lane = tid & 63;
  int quad = lane >> 4, l16 = lane & 15;
  int jhalf = wave >> 2, qq = wave & 3;

  // Q B-frags (B[k=quad*8+t][n=l16] = Q[q=l16][d=quad*8+t])
  f16x8 qfrag[2][2];
  float pq[2];
#pragma unroll
  for (int set = 0; set < 2; set++) {
    int q = q0 + qq * 32 + set * 16 + l16;
    const f16* Qrow = qb + ((size_t)bh * Lseq + q) * Dh;
    qfrag[set][0] = *reinterpret_cast<const f16x8*>(Qrow + quad * 8);
    qfrag[set][1] = *reinterpret_cast<const f16x8*>(Qrow + 32 + quad * 8);
    pq[set] = fmodf((float)q * PHI_F, 1.0f);
  }

  float pk[2][4];
#pragma unroll
  for (int jb = 0; jb < 2; jb++)
#pragma unroll
    for (int r = 0; r < 4; r++) {
      int j = jhalf * 32 + jb * 16 + quad * 4 + r;
      pk[jb][r] = fmodf((float)j * PHI_F, 1.0f);
    }

  // staging (per wave: 2 K-chunks + 2 V-chunks per period, one per sub-tile)
  // lds chunk (64*w + lane) holds global chunk gu of row (8w + lane>>3)
  const f16* Kbh = kb + (size_t)bh * Lseq * Dh;
  const f16* Vbh = vb + (size_t)bh * Dh * Lseq;  // tile-major
  const int gu = (lane & 7) ^ (lane >> 3);
  int g8 = wave * 8 + (lane >> 3);
  const f16* gK = Kbh + (size_t)g8 * Dh + gu * 8;  // + j0*Dh per tile
  const f16* gV = Vbh + (size_t)g8 * 64 + gu * 8;  // + j0*64 per tile
  f16* lK = Ks + wave * 512;   // sub-tile 1 at +4096
  f16* lV = Vs + wave * 512;

  const f16 one = (f16)1.0f;
  const f16x8 ones8 = {one, one, one, one, one, one, one, one};

  f32x4 acc_o[2][4] = {};  // [set][dblk]  O^T: row d=quad*4+r, col q=l16
  f32x4 acc_l[2] = {};     // row sums via ones-MFMA

  for (int j0 = 0; j0 < Lseq; j0 += 128) {
    __syncthreads();  // prior period's frag reads complete
    load16_to_lds(gK + (size_t)j0 * Dh, lK);
    load16_to_lds(gV + (size_t)j0 * 64, lV);
    load16_to_lds(gK + (size_t)(j0 + 64) * Dh, lK + 4096);
    load16_to_lds(gV + (size_t)(j0 + 64) * 64, lV + 4096);
    __syncthreads();  // compiler drains vmcnt before barrier

#pragma unroll
    for (int sub = 0; sub < 2; sub++) {
      const f16* Kc = Ks + sub * 4096;
      const f16* Vc = Vs + sub * 4096;

      // S^T = K * Q^T over this wave's 32 j's
      f32x4 accs[2][2] = {};
#pragma unroll
      for (int s = 0; s < 2; s++)
#pragma unroll
        for (int jb = 0; jb < 2; jb++) {
          f16x8 kf = *reinterpret_cast<const f16x8*>(
              Kc + (jhalf * 32 + jb * 16 + l16) * 64 +
              (((s * 4 + quad) ^ (l16 & 7)) * 8));
          accs[0][jb] = MFMA32(kf, qfrag[0][s], accs[0][jb]);
          accs[1][jb] = MFMA32(kf, qfrag[1][s], accs[1][jb]);
        }

      // p = exp2(s2 - |pq - pk|*log2e); pack K=32 PV B-frag (permuted
      // k-order: slot (quad,t) -> j = jhalf*32 + (t<4 ? quad*4+t
      // : 16+quad*4+(t-4)))
      f16x8 pf8[2];
#pragma unroll
      for (int set = 0; set < 2; set++) {
#pragma unroll
        for (int jb = 0; jb < 2; jb++) {
          float p[4];
#pragma unroll
          for (int r = 0; r < 4; r++) {
            float d = pq[set] - pk[jb][r];
            float arg = fmaf(-LOG2E, fabsf(d), accs[set][jb][r]);
            p[r] = __builtin_amdgcn_exp2f(arg);
          }
          auto lo = __builtin_amdgcn_cvt_pkrtz(p[0], p[1]);
          auto hi = __builtin_amdgcn_cvt_pkrtz(p[2], p[3]);
          pf8[set][jb * 4 + 0] = lo[0];
          pf8[set][jb * 4 + 1] = lo[1];
          pf8[set][jb * 4 + 2] = hi[0];
          pf8[set][jb * 4 + 3] = hi[1];
        }
        acc_l[set] = MFMA32(ones8, pf8[set], acc_l[set]);
      }
#pragma unroll
      for (int jb = 0; jb < 2; jb++)
#pragma unroll
        for (int r = 0; r < 4; r++)
          pk[jb][r] = __builtin_amdgcn_fractf(pk[jb][r] + CSTEP);

      // O^T += V^T * P^T  (A-frag = one b128 from permuted+swizzled Vs)
#pragma unroll
      for (int dblk = 0; dblk < 4; dblk++) {
        int row = dblk * 16 + l16;
        f16x8 va = *reinterpret_cast<const f16x8*>(
            Vc + row * 64 + (((jhalf * 4 + quad) ^ (l16 & 7)) * 8));
        acc_o[0][dblk] = MFMA32(va, pf8[0], acc_o[0][dblk]);
        acc_o[1][dblk] = MFMA32(va, pf8[1], acc_o[1][dblk]);
      }
    }
  }

  // combine jhalf partials: pure adds (static max => no rescale)
  __syncthreads();
  float* Oex = (float*)smem;              // [4 qq][2 set][4 dblk][16][16]
  float* Lex = (float*)(smem + 32768);    // [4 qq][2 set][16]
  if (jhalf == 1) {
#pragma unroll
    for (int set = 0; set < 2; set++) {
#pragma unroll
      for (int dblk = 0; dblk < 4; dblk++)
#pragma unroll
        for (int r = 0; r < 4; r++)
          Oex[(((qq * 2 + set) * 4 + dblk) * 16 + quad * 4 + r) * 16 + l16] =
              acc_o[set][dblk][r];
      if (quad == 0) Lex[(qq * 2 + set) * 16 + l16] = acc_l[set][0];
    }
  }
  __syncthreads();
  if (jhalf == 0) {
    int b = bh >> 4, h = bh & 15;
#pragma unroll
    for (int set = 0; set < 2; set++) {
      float ltot = acc_l[set][0] + Lex[(qq * 2 + set) * 16 + l16];
      float inv = 1.0f / ltot;
      int q = q0 + qq * 32 + set * 16 + l16;
      f16* crow = ctx + (size_t)(b * Lseq + q) * Dm + h * 64;
#pragma unroll
      for (int dblk = 0; dblk < 4; dblk++) {
        f16x4 o;
#pragma unroll
        for (int r = 0; r < 4; r++) {
          float full = acc_o[set][dblk][r] +
              Oex[(((qq * 2 + set) * 4 + dblk) * 16 + quad * 4 + r) * 16 + l16];
          o[r] = (f16)(full * inv);
        }
        *reinterpret_cast<uint2*>(crow + dblk * 16 + quad * 4) =
            *reinterpret_cast<uint2*>(&o);
      }
    }
  }
}

// ---------------------------------------------------------------------------
extern "C" void kernel_launch(void* const* d_in, const int* in_sizes, int n_in,
                              void* d_out, int out_size, void* d_ws, size_t ws_size,
                              hipStream_t stream) {
  const float* x      = (const float*)d_in[0];  // [2,2048,1024]
  const float* w_qkv  = (const float*)d_in[1];  // [1024,3072]
  const float* w_proj = (const float*)d_in[2];  // [1024,1024]
  const float* b_proj = (const float*)d_in[3];  // [1024]
  float* out = (float*)d_out;                   // [2,2048,1024]

  f16* xb    = (f16*)d_ws;                       // 4096*1024
  f16* wqkvT = xb + (size_t)Mtot * Dm;           // 3072*1024
  f16* wpT   = wqkvT + (size_t)NQKV * Dm;        // 1024*1024
  f16* qb    = wpT + (size_t)Dm * Dm;            // 32*2048*64
  f16* kb    = qb + (size_t)Bsz * H * Lseq * Dh;
  f16* vb    = kb + (size_t)Bsz * H * Lseq * Dh; // tile-major j-permuted
  f16* ctx   = vb + (size_t)Bsz * H * Lseq * Dh; // 4096*1024 attn output

  // fused prep: cast x + transpose w_qkv + transpose w_proj
  prep_fused<<<8192, 256, 0, stream>>>(x, xb, w_qkv, wqkvT, w_proj, wpT);

  // QKV GEMM: [4096,1024] x [1024,3072] -> q (scaled), k, v (v tile-major)
  gemm_f16<0><<<768, 256, 0, stream>>>(
      xb, wqkvT, Mtot, NQKV, Dm, qb, kb, vb, nullptr, nullptr);

  // attention (writes ctx)
  attn_kernel<<<512, 512, 0, stream>>>(qb, kb, vb, ctx);

  // proj GEMM: [4096,1024] x [1024,1024] + bias (64x128 tiles)
  gemm_f16<1><<<512, 256, 0, stream>>>(
      ctx, wpT, Mtot, Dm, Dm, nullptr, nullptr, nullptr, out, b_proj);
}